// Round 7
// baseline (333.441 us; speedup 1.0000x reference)
//
#include <hip/hip_runtime.h>
#include <hip/hip_bf16.h>
#include <climits>

// Voxel hash capacity: 2^22 slots for ~1.98M occupied voxels (load ~0.47).
#define HCAP (1 << 22)

__device__ __forceinline__ unsigned fmix32(unsigned h) {
    h ^= h >> 16; h *= 0x85ebca6bu;
    h ^= h >> 13; h *= 0xc2b2ae35u;
    h ^= h >> 16;
    return h;
}

// Gold model: XLA algebraic simplifier rewrites coord/0.02 into
// coord * (1/0.02f), and f32(1/0.02f) == 50.0f EXACTLY (50.0000011 is
// 0.29 ulp from 50). So gold quant = floor(round_f32(c*50)). The f32
// product rounds UP across an integer on ~60 of 6M coords (frac within
// ulp/2 below an integer) vs the exact 29-bit product — ~2 of those are
// rep-visible, matching the persistent absmax 1.066406 exactly.
__device__ __forceinline__ int quant(float c) {
    return (int)floorf(c * 50.0f);
}

// K0: init hash table
__global__ void k_init(int* __restrict__ kslot, int* __restrict__ vslot) {
    int i = blockIdx.x * blockDim.x + threadIdx.x;
    if (i < HCAP) { kslot[i] = -1; vslot[i] = INT_MAX; }
}

// K1: build hash (voxel key -> min point id), record slot per point
__global__ void k_build(const float* __restrict__ coord,
                        int* __restrict__ kslot, int* __restrict__ vslot,
                        int* __restrict__ slotp, int n) {
    int i = blockIdx.x * blockDim.x + threadIdx.x;
    if (i >= n) return;
    int g0 = quant(coord[i * 3 + 0]);
    int g1 = quant(coord[i * 3 + 1]);
    int g2 = quant(coord[i * 3 + 2]);
    int key = ((g0 & 1023) << 20) | ((g1 & 1023) << 10) | (g2 & 1023);

    unsigned h = fmix32((unsigned)key) & (HCAP - 1);
    int slot = -1;
    for (int probe = 0; probe < HCAP; ++probe) {
        int cur = kslot[h];
        if (cur == key) { slot = (int)h; break; }
        if (cur == -1) {
            int old = atomicCAS(&kslot[h], -1, key);
            if (old == -1 || old == key) { slot = (int)h; break; }
        }
        h = (h + 1) & (HCAP - 1);
    }
    atomicMin(&vslot[slot], i);
    slotp[i] = slot;
}

// K2: per 256-point block: resolve rep, stage 9 inputs/point in LDS,
// then emit 18 coalesced float4 stores per point.
__global__ void k_out(const float* __restrict__ feat, const float* __restrict__ coord,
                      const float* __restrict__ W, const float* __restrict__ Wc,
                      const int* __restrict__ slotp, const int* __restrict__ vslot,
                      float* __restrict__ out, int n) {
    __shared__ __align__(16) float wl[9 * 72];   // rows 0-5: W, rows 6-8: Wc
    __shared__ float pv[256 * 9];
    int t = threadIdx.x;
    for (int i = t; i < 648; i += 256) wl[i] = (i < 432) ? W[i] : Wc[i - 432];
    int base = blockIdx.x * 256;
    int p = base + t;
    if (p < n) {
        int r = vslot[slotp[p]];
        const float* fr = feat + (size_t)r * 6;
        const float* cr = coord + (size_t)r * 3;
        pv[t * 9 + 0] = fr[0]; pv[t * 9 + 1] = fr[1]; pv[t * 9 + 2] = fr[2];
        pv[t * 9 + 3] = fr[3]; pv[t * 9 + 4] = fr[4]; pv[t * 9 + 5] = fr[5];
        pv[t * 9 + 6] = cr[0]; pv[t * 9 + 7] = cr[1]; pv[t * 9 + 8] = cr[2];
    }
    __syncthreads();
    float4* out4 = (float4*)out;
    #pragma unroll
    for (int j = 0; j < 18; ++j) {
        int flat = j * 256 + t;              // [0, 4608) = 256 points x 18 groups
        int pl = flat / 18, c4 = flat - pl * 18;
        int pp = base + pl;
        if (pp < n) {
            const float* vals = &pv[pl * 9];
            float4 acc = make_float4(0.f, 0.f, 0.f, 0.f);
            #pragma unroll
            for (int q = 0; q < 9; ++q) {
                float v = vals[q];
                float4 wv = *(const float4*)&wl[q * 72 + c4 * 4];
                acc.x = fmaf(v, wv.x, acc.x);
                acc.y = fmaf(v, wv.y, acc.y);
                acc.z = fmaf(v, wv.z, acc.z);
                acc.w = fmaf(v, wv.w, acc.w);
            }
            out4[(size_t)pp * 18 + c4] = acc;
        }
    }
}

extern "C" void kernel_launch(void* const* d_in, const int* in_sizes, int n_in,
                              void* d_out, int out_size, void* d_ws, size_t ws_size,
                              hipStream_t stream) {
    const float* coord = (const float*)d_in[0];
    const float* feat  = (const float*)d_in[1];
    const float* W     = (const float*)d_in[2];
    const float* Wc    = (const float*)d_in[3];
    float* out = (float*)d_out;
    int n = in_sizes[0] / 3;

    // ws_size confirmed 2.3 GB; we need 40 MB.
    int* kslot = (int*)d_ws;
    int* vslot = kslot + HCAP;
    int* slotp = vslot + HCAP;

    k_init<<<(HCAP + 255) / 256, 256, 0, stream>>>(kslot, vslot);
    k_build<<<(n + 255) / 256, 256, 0, stream>>>(coord, kslot, vslot, slotp, n);
    k_out<<<(n + 255) / 256, 256, 0, stream>>>(feat, coord, W, Wc, slotp, vslot, out, n);
}

// Round 9
// 261.021 us; speedup vs baseline: 1.2774x; 1.2774x over previous
//
#include <hip/hip_runtime.h>
#include <hip/hip_bf16.h>
#include <climits>

// Voxel hash: 2^22 u64 slots (key<<32 | min_point_id), ~1.98M voxels, load 0.47.
#define HCAP (1 << 22)
typedef unsigned long long u64;
typedef float f32x4 __attribute__((ext_vector_type(4)));
#define EMPTY64 0xFFFFFFFFFFFFFFFFULL

__device__ __forceinline__ unsigned fmix32(unsigned h) {
    h ^= h >> 16; h *= 0x85ebca6bu;
    h ^= h >> 13; h *= 0xc2b2ae35u;
    h ^= h >> 16;
    return h;
}

// Gold quant (verified round 7): XLA rewrites /0.02 -> *(1/0.02f), and
// f32(1/0.02f) == 50.0f exactly. One f32 RN multiply + floor.
__device__ __forceinline__ int quant(float c) {
    return (int)floorf(c * 50.0f);
}

// K0: init packed table to EMPTY (16B vector stores)
__global__ void k_init(u64* __restrict__ tab) {
    int i = blockIdx.x * blockDim.x + threadIdx.x;
    if (i < HCAP / 2) {
        ulonglong2 v; v.x = EMPTY64; v.y = EMPTY64;
        ((ulonglong2*)tab)[i] = v;
    }
}

// K1: one CAS-claim or CAS-min per point into the packed table.
// Slot lifecycle: EMPTY -> (key,id) with id monotonically decreasing; key
// never changes after claim, so stale plain reads are always re-validated
// by the CAS and the min loop cannot livelock (ids strictly decrease).
__global__ void k_build(const float* __restrict__ coord,
                        u64* __restrict__ tab, int* __restrict__ slotp, int n) {
    int i = blockIdx.x * blockDim.x + threadIdx.x;
    if (i >= n) return;
    int g0 = quant(coord[i * 3 + 0]);
    int g1 = quant(coord[i * 3 + 1]);
    int g2 = quant(coord[i * 3 + 2]);
    unsigned key = ((unsigned)(g0 & 1023) << 20) | ((unsigned)(g1 & 1023) << 10)
                 | (unsigned)(g2 & 1023);
    u64 packed = ((u64)key << 32) | (unsigned)i;

    unsigned h = fmix32(key) & (HCAP - 1);
    int slot = -1;
    while (slot < 0) {
        u64 cur = tab[h];
        if (cur == EMPTY64) {
            u64 old = atomicCAS(&tab[h], EMPTY64, packed);
            if (old == EMPTY64) { slot = (int)h; break; }
            cur = old;
        }
        if ((unsigned)(cur >> 32) == key) {
            while ((unsigned)cur > (unsigned)i) {   // current min id > ours
                u64 old = atomicCAS(&tab[h], cur, packed);
                if (old == cur) break;
                cur = old;                          // key is stable post-claim
            }
            slot = (int)h;
            break;
        }
        h = (h + 1) & (HCAP - 1);
    }
    slotp[i] = slot;
}

// K2: per 256-point block: resolve rep (low dword of slot), stage 9
// inputs/point in LDS, 18 coalesced NON-TEMPORAL float4 stores per point
// (out is write-once; keep L2 for the table/feat/coord gathers).
__global__ void k_out(const float* __restrict__ feat, const float* __restrict__ coord,
                      const float* __restrict__ W, const float* __restrict__ Wc,
                      const int* __restrict__ slotp, const u64* __restrict__ tab,
                      float* __restrict__ out, int n) {
    __shared__ __align__(16) float wl[9 * 72];   // rows 0-5: W, rows 6-8: Wc
    __shared__ float pv[256 * 9];
    int t = threadIdx.x;
    for (int i = t; i < 648; i += 256) wl[i] = (i < 432) ? W[i] : Wc[i - 432];
    int base = blockIdx.x * 256;
    int p = base + t;
    if (p < n) {
        int r = (int)(unsigned)(tab[slotp[p]] & 0xFFFFFFFFu);  // min point id
        const float* fr = feat + (size_t)r * 6;
        const float* cr = coord + (size_t)r * 3;
        pv[t * 9 + 0] = fr[0]; pv[t * 9 + 1] = fr[1]; pv[t * 9 + 2] = fr[2];
        pv[t * 9 + 3] = fr[3]; pv[t * 9 + 4] = fr[4]; pv[t * 9 + 5] = fr[5];
        pv[t * 9 + 6] = cr[0]; pv[t * 9 + 7] = cr[1]; pv[t * 9 + 8] = cr[2];
    }
    __syncthreads();
    f32x4* out4 = (f32x4*)out;
    #pragma unroll
    for (int j = 0; j < 18; ++j) {
        int flat = j * 256 + t;              // [0, 4608) = 256 points x 18 groups
        int pl = flat / 18, c4 = flat - pl * 18;
        int pp = base + pl;
        if (pp < n) {
            const float* vals = &pv[pl * 9];
            f32x4 acc = (f32x4)(0.f);
            #pragma unroll
            for (int q = 0; q < 9; ++q) {
                float v = vals[q];
                f32x4 wv = *(const f32x4*)&wl[q * 72 + c4 * 4];
                acc.x = fmaf(v, wv.x, acc.x);
                acc.y = fmaf(v, wv.y, acc.y);
                acc.z = fmaf(v, wv.z, acc.z);
                acc.w = fmaf(v, wv.w, acc.w);
            }
            __builtin_nontemporal_store(acc, &out4[(size_t)pp * 18 + c4]);
        }
    }
}

extern "C" void kernel_launch(void* const* d_in, const int* in_sizes, int n_in,
                              void* d_out, int out_size, void* d_ws, size_t ws_size,
                              hipStream_t stream) {
    const float* coord = (const float*)d_in[0];
    const float* feat  = (const float*)d_in[1];
    const float* W     = (const float*)d_in[2];
    const float* Wc    = (const float*)d_in[3];
    float* out = (float*)d_out;
    int n = in_sizes[0] / 3;

    // ws_size = 2.3 GB; we use 40 MB.
    u64* tab   = (u64*)d_ws;
    int* slotp = (int*)(tab + HCAP);

    k_init<<<(HCAP / 2 + 255) / 256, 256, 0, stream>>>(tab);
    k_build<<<(n + 255) / 256, 256, 0, stream>>>(coord, tab, slotp, n);
    k_out<<<(n + 255) / 256, 256, 0, stream>>>(feat, coord, W, Wc, slotp, tab, out, n);
}